// Round 7
// baseline (241.837 us; speedup 1.0000x reference)
//
#include <hip/hip_runtime.h>

// TorchPatchNN: unfold(7x7) -> NN argmin over 8100 keys (D=147) -> gather value -> fold mean.
// Round 7: barrier-free K-loop, Q in LDS (R6's Q-in-VGPR spilled: 65 MB scratch writes).
//  - Per block: Q tile 80 KB LDS filled once via global_load_lds, ONE barrier; then
//    8 kt-tiles x 5 chunks with NO barriers: A from LDS (lane-contiguous b128), B streamed
//    global->VGPR from L2 (frag-order layout, coalesced dwordx4).
//  - Per-row running argmin in 32 regs (strict < valid: per-lane n strictly ascending);
//    end-of-kernel tie-aware shfl_xor butterfly over l15, 2 KB aliased-LDS wave-pair
//    combine, one packed-u64 atomicMin per q.
//  - Regs ~210 < 256 @ 2 waves/SIMD; LDS 80 KB -> exactly 2 blocks/CU.
// Numerics unchanged (fp16 h + 2^-11*l split, 3 MFMA passes): absmax 0 for 4 rounds.

#define NQ 8100
#define NK 8100
#define DD 147
#define HO 90
#define IMG 96
#define NCH 5                 // K chunks of 32 (160 padded K)
#define CST 262144            // f16 per chunk plane: 512 groups x 512
#define ARRN (NCH * CST)      // f16 per array

typedef _Float16 half8 __attribute__((ext_vector_type(8)));
typedef float f32x4 __attribute__((ext_vector_type(4)));

__device__ __forceinline__ void gld16(const _Float16* g, _Float16* l) {
    __builtin_amdgcn_global_load_lds(
        (const __attribute__((address_space(1))) unsigned int*)g,
        (__attribute__((address_space(3))) unsigned int*)l, 16, 0, 0);
}

// ---------------- prep: split Q/K into fp16 hi/lo (frag order) + key norms + init ---------
__global__ void k_prep(const float* __restrict__ query, const float* __restrict__ key,
                       _Float16* __restrict__ Qh, _Float16* __restrict__ Ql,
                       _Float16* __restrict__ Kh, _Float16* __restrict__ Kl,
                       float* __restrict__ kn, unsigned long long* __restrict__ fidx64) {
    const int bx = blockIdx.x;
    const bool isK = (blockIdx.y != 0);

    if (bx >= 640) {                      // fused k_kn region: 128 blocks on y==1
        if (!isK) return;
        int wave = threadIdx.x >> 6, lane = threadIdx.x & 63;
        int kb = ((bx - 640) * 4 + wave) * 16;
        for (int r = 0; r < 16; ++r) {
            int k = kb + r;
            float s = 0.f;
            if (k < NK)
                for (int d = lane; d < DD; d += 64) {
                    float v = key[k * DD + d];
                    s += v * v;
                }
#pragma unroll
            for (int off = 32; off; off >>= 1) s += __shfl_down(s, off, 64);
            if (lane == 0) {
                kn[k] = (k < NK) ? s : 1e30f;
                fidx64[k] = 0xFFFFFFFFFFFFFFFFull;   // ws re-poisoned every launch
            }
        }
        return;
    }

    int t = bx * 256 + threadIdx.x;             // 0 .. 163839 (ARRN/8)
    int c = t >> 15;                            // chunk
    int rem = t & 32767;                        // g*64 + lane
    int col = ((rem >> 6) << 4) + (rem & 15);   // g*16 + l15
    int quad = (rem >> 4) & 3;
    int kbase = c * 32 + quad * 8;

    float v[8];
#pragma unroll
    for (int j = 0; j < 8; ++j) {
        int k = kbase + j;
        float x = 0.f;
        if (k < DD && col < NQ) {
            if (isK) {
                x = key[col * DD + k];
            } else {
                int c3 = k / 49, r2 = k - 49 * c3;
                int rr = r2 / 7, ss = r2 - 7 * rr;
                int y = col / HO, xx = col - HO * y;
                x = query[(c3 * IMG + y + rr) * IMG + xx + ss];
            }
        }
        v[j] = x;
    }
    half8 h8, l8;
#pragma unroll
    for (int j = 0; j < 8; ++j) {
        _Float16 h = (_Float16)v[j];
        h8[j] = h;
        l8[j] = (_Float16)((v[j] - (float)h) * 2048.0f);
    }
    if (isK) {
        *(half8*)(Kh + t * 8) = h8;
        *(half8*)(Kl + t * 8) = l8;
    } else {
        *(half8*)(Qh + t * 8) = h8;
        *(half8*)(Ql + t * 8) = l8;
    }
}

// ---------------- main: split-f16 MFMA Q.K^T + fused argmin, barrier-free K-loop ----------
__launch_bounds__(256, 2)
__global__ void k_nn(const _Float16* __restrict__ Qh, const _Float16* __restrict__ Ql,
                     const _Float16* __restrict__ Kh, const _Float16* __restrict__ Kl,
                     const float* __restrict__ kn, unsigned long long* __restrict__ out) {
    // Q tile: sQh 5c x 8g x 512 f16 = 40 KB, sQl likewise. Epilogue red[] aliases in.
    __shared__ __align__(16) char smem[81920];
    _Float16* sQh = (_Float16*)smem;
    _Float16* sQl = (_Float16*)(smem + 40960);

    const int tid = (int)threadIdx.x;
    const int wave = tid >> 6, lane = tid & 63;
    const int l15 = lane & 15, quad = lane >> 4;
    const int mbase = (wave >> 1) * 64;           // wave tile 64x64 within 128x128
    const int nbase = (wave & 1) * 64;

    // XCD rectangle: 16 qt x 32 kt per XCD (K slab 2.56 MB ~ L2-resident).
    const int b = (int)blockIdx.x;                // 512 blocks: 64 qt x 8 kt-groups
    const int xcd = b & 7;
    const int i = b >> 3;                         // 0..63
    const int qt = (xcd >> 1) * 16 + (i & 15);
    const int ktbase = ((xcd & 1) * 4 + (i >> 4)) * 8;   // 8 kt tiles per block
    const int q0 = qt * 128;

    // ---- fill Q LDS: 80 segments of 1 KiB, 20 per wave, one barrier ----
    {
        const _Float16* gq = (const _Float16*)(lane * 8);
#pragma unroll
        for (int s = 0; s < 20; ++s) {
            int seg = s * 4 + wave;               // 0..79
            int a = seg / 40, rem = seg % 40;
            int c = rem >> 3, g = rem & 7;
            const _Float16* gp = (a ? Ql : Qh) + c * CST + (qt * 8 + g) * 512 + lane * 8;
            _Float16* ld = (_Float16*)smem + a * 20480 + (c * 8 + g) * 512 + lane * 8;
            gld16(gp, ld);
        }
        (void)gq;
    }
    __syncthreads();

    float rbv[16];
    int rbn[16];
#pragma unroll
    for (int r = 0; r < 16; ++r) { rbv[r] = 1e38f; rbn[r] = 0x7fffffff; }

    const int agrp = (mbase >> 4);
    const int bgrp = (nbase >> 4);

    for (int t = 0; t < 8; ++t) {
        const int kts = ktbase + t;
        f32x4 acc0[4][4], acc1[4][4];
#pragma unroll
        for (int ii = 0; ii < 4; ++ii)
#pragma unroll
            for (int jj = 0; jj < 4; ++jj) {
                acc0[ii][jj] = (f32x4)0.f;
                acc1[ii][jj] = (f32x4)0.f;
            }

        const int kgoff = (kts * 8 + bgrp) * 512 + lane * 8;
#pragma unroll
        for (int c = 0; c < NCH; ++c) {
            half8 ah[4], al[4];
#pragma unroll
            for (int mt = 0; mt < 4; ++mt) {
                int aoff = c * 4096 + (agrp + mt) * 512 + lane * 8;
                ah[mt] = *(const half8*)(sQh + aoff);
                al[mt] = *(const half8*)(sQl + aoff);
            }
#pragma unroll
            for (int nt = 0; nt < 4; ++nt) {
                half8 bh = *(const half8*)(Kh + c * CST + kgoff + nt * 512);
                half8 bl = *(const half8*)(Kl + c * CST + kgoff + nt * 512);
#pragma unroll
                for (int mt = 0; mt < 4; ++mt) {
                    acc0[mt][nt] = __builtin_amdgcn_mfma_f32_16x16x32_f16(ah[mt], bh, acc0[mt][nt], 0, 0, 0);
                    acc1[mt][nt] = __builtin_amdgcn_mfma_f32_16x16x32_f16(ah[mt], bl, acc1[mt][nt], 0, 0, 0);
                    acc1[mt][nt] = __builtin_amdgcn_mfma_f32_16x16x32_f16(al[mt], bh, acc1[mt][nt], 0, 0, 0);
                }
            }
        }

        // dist = kn - 2*(acc0 + acc1/2048); update per-row running best in regs.
        // Per-lane n strictly ascends (tiles asc, nt asc) -> strict < == first-occurrence.
#pragma unroll
        for (int nt = 0; nt < 4; ++nt) {
            int n = kts * 128 + nbase + nt * 16 + l15;
            float knv = kn[n];
#pragma unroll
            for (int mt = 0; mt < 4; ++mt)
#pragma unroll
                for (int r = 0; r < 4; ++r) {
                    float d = knv - 2.0f * (acc0[mt][nt][r] + acc1[mt][nt][r] * (1.0f / 2048.0f));
                    int ri = mt * 4 + r;
                    if (d < rbv[ri]) { rbv[ri] = d; rbn[ri] = n; }
                }
        }
    }

    // ---- final reduce: tie-aware butterfly over the 16 l15 lanes ----
#pragma unroll
    for (int ri = 0; ri < 16; ++ri) {
#pragma unroll
        for (int m = 1; m < 16; m <<= 1) {
            float vo = __shfl_xor(rbv[ri], m, 64);
            int no = __shfl_xor(rbn[ri], m, 64);
            if (vo < rbv[ri] || (vo == rbv[ri] && no < rbn[ri])) { rbv[ri] = vo; rbn[ri] = no; }
        }
    }

    __syncthreads();   // all waves done reading Q LDS; safe to alias red[] into it
    float* redv = (float*)smem;            // [128][2]
    int* redi = (int*)(smem + 1024);       // [128][2]
    if (l15 == 0) {
#pragma unroll
        for (int mt = 0; mt < 4; ++mt)
#pragma unroll
            for (int r = 0; r < 4; ++r) {
                int m = mbase + mt * 16 + quad * 4 + r;   // C layout row
                redv[m * 2 + (wave & 1)] = rbv[mt * 4 + r];
                redi[m * 2 + (wave & 1)] = rbn[mt * 4 + r];
            }
    }
    __syncthreads();

    if (tid < 128) {
        float v0 = redv[tid * 2], v1 = redv[tid * 2 + 1];
        int n0 = redi[tid * 2], n1 = redi[tid * 2 + 1];
        if (v1 < v0 || (v1 == v0 && n1 < n0)) { v0 = v1; n0 = n1; }
        unsigned u = __float_as_uint(v0);
        u = (u & 0x80000000u) ? ~u : (u | 0x80000000u);   // order-preserving map
        unsigned long long pk = ((unsigned long long)u << 32) | (unsigned)n0;
        atomicMin(&out[q0 + tid], pk);
    }
}

// ---------------- gather + fold (overlap-add mean) ----------------
__global__ void k_fold(const float* __restrict__ value,
                       const unsigned long long* __restrict__ fidx64,
                       float* __restrict__ out) {
    int t = blockIdx.x * 256 + threadIdx.x;   // 3*96*96 = 27648
    if (t >= 3 * IMG * IMG) return;
    int c = t / (IMG * IMG);
    int rem = t % (IMG * IMG);
    int Y = rem / IMG, X = rem % IMG;
    int i0 = max(0, Y - (HO - 1)), i1 = min(6, Y);
    int j0 = max(0, X - (HO - 1)), j1 = min(6, X);
    float s = 0.f;
    for (int i = i0; i <= i1; ++i)
        for (int j = j0; j <= j1; ++j) {
            int p = (Y - i) * HO + (X - j);
            int row = (int)(fidx64[p] & 0xFFFFFFFFull);
            s += value[row * DD + c * 49 + i * 7 + j];
        }
    float cnt = (float)((i1 - i0 + 1) * (j1 - j0 + 1));
    out[t] = s / cnt;
}

extern "C" void kernel_launch(void* const* d_in, const int* in_sizes, int n_in,
                              void* d_out, int out_size, void* d_ws, size_t ws_size,
                              hipStream_t stream) {
    const float* query = (const float*)d_in[0];
    const float* key   = (const float*)d_in[1];
    const float* value = (const float*)d_in[2];
    float* out = (float*)d_out;

    _Float16* Qh = (_Float16*)d_ws;           // ARRN f16 each
    _Float16* Ql = Qh + ARRN;
    _Float16* Kh = Ql + ARRN;
    _Float16* Kl = Kh + ARRN;
    float* kn = (float*)(Kl + ARRN);          // 8192 f32
    unsigned long long* fidx64 = (unsigned long long*)(kn + 8192);   // 8192 u64

    dim3 gp(768, 2);   // 640 split blocks + 128 fused-kn blocks (y==1)
    k_prep<<<gp, 256, 0, stream>>>(query, key, Qh, Ql, Kh, Kl, kn, fidx64);
    k_nn<<<512, 256, 0, stream>>>(Qh, Ql, Kh, Kl, kn, fidx64);
    k_fold<<<108, 256, 0, stream>>>(value, fidx64, out);
}

// Round 8
// 192.888 us; speedup vs baseline: 1.2538x; 1.2538x over previous
//
#include <hip/hip_runtime.h>

// TorchPatchNN: unfold(7x7) -> NN argmin over 8100 keys (D=147) -> gather value -> fold mean.
// Round 8: fit the barrier-free design in the 2-waves/SIMD register budget.
//   R6/R7 spilled (65/126 MB scratch): 128-reg acc + frags > 256-reg cap. Now 8-wave blocks,
//   wave tile 64x32 -> acc 64 regs, total ~190. Q unfold+split fused into k_main's LDS fill
//   (no Q global round trip); K split rebuilt coalesced (old prep did stride-588B scalar
//   reads); B frags streamed global->VGPR with explicit next-chunk register prefetch.
//   256 blocks (1/CU), XCD rectangles 16qt x 2ktg (3.9 MB < 4 MiB L2), zero K-loop barriers.
// Numerics unchanged (fp16 h + 2^-11*l split, 3 MFMA passes, tie-aware u64 atomicMin).

#define NQ 8100
#define NK 8100
#define DD 147
#define HO 90
#define IMG 96
#define NCH 5                 // K chunks of 32 (160 padded K)
#define CST 262144            // f16 per chunk plane: 512 groups x 512

typedef _Float16 half8 __attribute__((ext_vector_type(8)));
typedef float f32x4 __attribute__((ext_vector_type(4)));

// ---------------- K prep: coalesced LDS-staged split + kn + sentinel init ----------------
__global__ void k_kprep(const float* __restrict__ key, _Float16* __restrict__ Kh,
                        _Float16* __restrict__ Kl, float* __restrict__ kn,
                        unsigned long long* __restrict__ fidx64) {
    __shared__ float lk[16 * 148];
    const int b = blockIdx.x, tid = (int)threadIdx.x;   // 512 blocks x 16 keys
    for (int u = tid; u < 16 * 147; u += 256) {
        int gi = b * 2352 + u;
        lk[(u / 147) * 148 + (u % 147)] = (gi < NK * DD) ? key[gi] : 0.f;
    }
    __syncthreads();
    for (int u = tid; u < 320; u += 256) {              // 16 keys x 20 half8 per array
        int kl_ = u / 20, t20 = u % 20;
        int c = t20 >> 2, quad = t20 & 3, kbase = c * 32 + quad * 8;
        int col = b * 16 + kl_;
        half8 h8, l8;
#pragma unroll
        for (int j = 0; j < 8; ++j) {
            int k = kbase + j;
            float v = (k < DD) ? lk[kl_ * 148 + k] : 0.f;
            _Float16 h = (_Float16)v;
            h8[j] = h;
            l8[j] = (_Float16)((v - (float)h) * 2048.0f);
        }
        int lane = quad * 16 + (col & 15);
        int idx = c * CST + (col >> 4) * 512 + lane * 8;
        *(half8*)(Kh + idx) = h8;
        *(half8*)(Kl + idx) = l8;
    }
    if (tid < 16) {
        int col = b * 16 + tid;
        float s = 0.f;
        for (int d = 0; d < DD; ++d) { float v = lk[tid * 148 + d]; s += v * v; }
        kn[col] = (col < NK) ? s : 1e30f;
        fidx64[col] = 0xFFFFFFFFFFFFFFFFull;   // atomicMin sentinel (ws re-poisoned)
    }
}

// ---------------- main: Q prep->LDS + barrier-free split-f16 MFMA NN sweep ----------------
__launch_bounds__(512, 2)
__global__ void k_main(const float* __restrict__ query, const _Float16* __restrict__ Kh,
                       const _Float16* __restrict__ Kl, const float* __restrict__ kn,
                       unsigned long long* __restrict__ out) {
    __shared__ __align__(16) char smem[81920];   // sQh 40 KB + sQl 40 KB; epilogue aliases
    _Float16* sQh = (_Float16*)smem;
    _Float16* sQl = (_Float16*)(smem + 40960);

    const int tid = (int)threadIdx.x;
    const int wave = tid >> 6, lane = tid & 63;
    const int l15 = lane & 15, quad = lane >> 4;

    // XCD rectangle: 16 qt x 2 ktg per XCD -> Q 1.31 MB + K 2.62 MB < 4 MiB L2.
    const int b = (int)blockIdx.x;               // 256 blocks = 64 qt x 4 ktg
    const int xcd = b & 7, i = b >> 3;           // i: 0..31
    const int qt = (xcd >> 1) * 16 + (i & 15);
    const int ktg = (xcd & 1) * 2 + (i >> 4);
    const int ktbase = ktg * 16;                 // 16 kt tiles per block
    const int q0 = qt * 128;

    // ---- Q tile: unfold + fp16 split straight into LDS (frag order), 5 half8/thread ----
#pragma unroll
    for (int s = 0; s < 5; ++s) {
        int h8i = s * 512 + tid;                 // 0..2559
        int c = h8i >> 9, r = h8i & 511;
        int g = r >> 6, ln = r & 63;
        int gcol = q0 + g * 16 + (ln & 15);
        int kbase = c * 32 + (ln >> 4) * 8;
        int y = gcol / HO, x = gcol - y * HO;
        half8 h8, l8;
#pragma unroll
        for (int j = 0; j < 8; ++j) {
            int k = kbase + j;
            float v = 0.f;
            if (k < DD && gcol < NQ) {
                int c3 = k / 49, r2 = k - 49 * c3;
                int rr = r2 / 7, ss = r2 - 7 * rr;
                v = query[(c3 * IMG + y + rr) * IMG + x + ss];
            }
            _Float16 h = (_Float16)v;
            h8[j] = h;
            l8[j] = (_Float16)((v - (float)h) * 2048.0f);
        }
        *(half8*)(sQh + h8i * 8) = h8;
        *(half8*)(sQl + h8i * 8) = l8;
    }
    __syncthreads();   // the ONLY barrier before the final reduce

    const int mbase = (wave >> 2) * 64;          // wave tile 64x32 within 128x128
    const int nq = wave & 3, nbase = nq * 32;
    const int agrp = (wave >> 2) * 4;
    const int bgrp = nq * 2;

    float rbv[16];
    int rbn[16];
#pragma unroll
    for (int r = 0; r < 16; ++r) { rbv[r] = 1e38f; rbn[r] = 0x7fffffff; }

    for (int t = 0; t < 16; ++t) {
        const int kts = ktbase + t;
        f32x4 acc0[4][2], acc1[4][2];
#pragma unroll
        for (int mt = 0; mt < 4; ++mt)
#pragma unroll
            for (int nt = 0; nt < 2; ++nt) {
                acc0[mt][nt] = (f32x4)0.f;
                acc1[mt][nt] = (f32x4)0.f;
            }

        const int kb0 = (kts * 8 + bgrp) * 512 + lane * 8;
        half8 bh[2][2], bl[2][2];                // [parity][nt] double-buffered B frags
        bh[0][0] = *(const half8*)(Kh + kb0);
        bh[0][1] = *(const half8*)(Kh + kb0 + 512);
        bl[0][0] = *(const half8*)(Kl + kb0);
        bl[0][1] = *(const half8*)(Kl + kb0 + 512);

#pragma unroll
        for (int c = 0; c < NCH; ++c) {
            const int cur = c & 1, nxt = cur ^ 1;
            if (c + 1 < NCH) {                   // prefetch next chunk's B into regs
                const int kbn = (c + 1) * CST + kb0;
                bh[nxt][0] = *(const half8*)(Kh + kbn);
                bh[nxt][1] = *(const half8*)(Kh + kbn + 512);
                bl[nxt][0] = *(const half8*)(Kl + kbn);
                bl[nxt][1] = *(const half8*)(Kl + kbn + 512);
            }
            half8 ah[4], al[4];
#pragma unroll
            for (int mt = 0; mt < 4; ++mt) {
                int aoff = (c * 8 + agrp + mt) * 512 + lane * 8;
                ah[mt] = *(const half8*)(sQh + aoff);
                al[mt] = *(const half8*)(sQl + aoff);
            }
#pragma unroll
            for (int nt = 0; nt < 2; ++nt)
#pragma unroll
                for (int mt = 0; mt < 4; ++mt) {
                    acc0[mt][nt] = __builtin_amdgcn_mfma_f32_16x16x32_f16(ah[mt], bh[cur][nt], acc0[mt][nt], 0, 0, 0);
                    acc1[mt][nt] = __builtin_amdgcn_mfma_f32_16x16x32_f16(ah[mt], bl[cur][nt], acc1[mt][nt], 0, 0, 0);
                    acc1[mt][nt] = __builtin_amdgcn_mfma_f32_16x16x32_f16(al[mt], bh[cur][nt], acc1[mt][nt], 0, 0, 0);
                }
        }

        // dist = kn - 2*(acc0 + acc1/2048); per-lane n strictly ascends (t asc, nt asc)
#pragma unroll
        for (int nt = 0; nt < 2; ++nt) {
            int n = kts * 128 + nbase + nt * 16 + l15;
            float knv = kn[n];
#pragma unroll
            for (int mt = 0; mt < 4; ++mt)
#pragma unroll
                for (int r = 0; r < 4; ++r) {
                    float d = knv - 2.0f * (acc0[mt][nt][r] + acc1[mt][nt][r] * (1.0f / 2048.0f));
                    int ri = mt * 4 + r;
                    if (d < rbv[ri]) { rbv[ri] = d; rbn[ri] = n; }
                }
        }
    }

    // ---- tie-aware butterfly over the 16 l15 lanes (xor<16 keeps quad fixed) ----
#pragma unroll
    for (int ri = 0; ri < 16; ++ri) {
#pragma unroll
        for (int m = 1; m < 16; m <<= 1) {
            float vo = __shfl_xor(rbv[ri], m, 64);
            int no = __shfl_xor(rbn[ri], m, 64);
            if (vo < rbv[ri] || (vo == rbv[ri] && no < rbn[ri])) { rbv[ri] = vo; rbn[ri] = no; }
        }
    }

    __syncthreads();   // Q LDS dead; alias the per-row combine buffers
    float* redv = (float*)smem;            // [128][5] f32 (stride pad)
    int* redi = (int*)(smem + 128 * 5 * 4);
    if (l15 == 0) {
#pragma unroll
        for (int mt = 0; mt < 4; ++mt)
#pragma unroll
            for (int r = 0; r < 4; ++r) {
                int row = mbase + mt * 16 + quad * 4 + r;   // C layout: row = quad*4 + reg
                redv[row * 5 + nq] = rbv[mt * 4 + r];
                redi[row * 5 + nq] = rbn[mt * 4 + r];
            }
    }
    __syncthreads();

    if (tid < 128) {
        float bv = 1e38f;
        int bn = 0x7fffffff;
#pragma unroll
        for (int k = 0; k < 4; ++k) {          // nq ascending == n-range ascending
            float v = redv[tid * 5 + k];
            int n = redi[tid * 5 + k];
            if (v < bv || (v == bv && n < bn)) { bv = v; bn = n; }
        }
        unsigned u = __float_as_uint(bv);
        u = (u & 0x80000000u) ? ~u : (u | 0x80000000u);   // order-preserving map
        unsigned long long pk = ((unsigned long long)u << 32) | (unsigned)bn;
        atomicMin(&out[q0 + tid], pk);
    }
}

// ---------------- gather + fold (overlap-add mean) ----------------
__global__ void k_fold(const float* __restrict__ value,
                       const unsigned long long* __restrict__ fidx64,
                       float* __restrict__ out) {
    int t = blockIdx.x * 256 + threadIdx.x;   // 3*96*96 = 27648
    if (t >= 3 * IMG * IMG) return;
    int c = t / (IMG * IMG);
    int rem = t % (IMG * IMG);
    int Y = rem / IMG, X = rem % IMG;
    int i0 = max(0, Y - (HO - 1)), i1 = min(6, Y);
    int j0 = max(0, X - (HO - 1)), j1 = min(6, X);
    float s = 0.f;
    for (int i = i0; i <= i1; ++i)
        for (int j = j0; j <= j1; ++j) {
            int p = (Y - i) * HO + (X - j);
            int row = (int)(fidx64[p] & 0xFFFFFFFFull);
            s += value[row * DD + c * 49 + i * 7 + j];
        }
    float cnt = (float)((i1 - i0 + 1) * (j1 - j0 + 1));
    out[t] = s / cnt;
}

extern "C" void kernel_launch(void* const* d_in, const int* in_sizes, int n_in,
                              void* d_out, int out_size, void* d_ws, size_t ws_size,
                              hipStream_t stream) {
    const float* query = (const float*)d_in[0];
    const float* key   = (const float*)d_in[1];
    const float* value = (const float*)d_in[2];
    float* out = (float*)d_out;

    _Float16* Kh = (_Float16*)d_ws;                      // NCH*CST f16 each
    _Float16* Kl = Kh + NCH * CST;
    float* kn = (float*)(Kl + NCH * CST);                // 8192 f32
    unsigned long long* fidx64 = (unsigned long long*)(kn + 8192);   // 8192 u64

    k_kprep<<<512, 256, 0, stream>>>(key, Kh, Kl, kn, fidx64);
    k_main<<<256, 512, 0, stream>>>(query, Kh, Kl, kn, fidx64);
    k_fold<<<108, 256, 0, stream>>>(value, fidx64, out);
}